// Round 3
// baseline (6441.998 us; speedup 1.0000x reference)
//
#include <hip/hip_runtime.h>

#define N_NODES  50000
#define N_EDGES  600000
#define DIM      128
#define N_LAYERS 5
#define N_GRAPHS 512
#define NB       ((N_NODES + 255) / 256)   // 196 scan blocks
#define GEMM_GRID 1250
#define GEMM_ITERS 5                        // 1250*5*8 = 50000 rows exactly

// ---------------------------------------------------------------- preprocess

__global__ void k_count(const int* __restrict__ dst, int* __restrict__ cnt) {
    int e = blockIdx.x * blockDim.x + threadIdx.x;
    if (e < N_EDGES) atomicAdd(&cnt[dst[e]], 1);
}

__global__ __launch_bounds__(256) void k_bsum(const int* __restrict__ cnt,
                                              int* __restrict__ bsum) {
    __shared__ int ws[4];
    int i = blockIdx.x * 256 + threadIdx.x;
    int v = (i < N_NODES) ? cnt[i] : 0;
#pragma unroll
    for (int o = 32; o > 0; o >>= 1) v += __shfl_down(v, o, 64);
    if ((threadIdx.x & 63) == 0) ws[threadIdx.x >> 6] = v;
    __syncthreads();
    if (threadIdx.x == 0) bsum[blockIdx.x] = ws[0] + ws[1] + ws[2] + ws[3];
}

__global__ void k_scan_bsum(const int* __restrict__ bsum, int* __restrict__ boff) {
    __shared__ int s[256];
    int t = threadIdx.x;
    int v = (t < NB) ? bsum[t] : 0;
    s[t] = v;
    __syncthreads();
    for (int o = 1; o < 256; o <<= 1) {
        int u = (t >= o) ? s[t - o] : 0;
        __syncthreads();
        s[t] += u;
        __syncthreads();
    }
    if (t < NB) boff[t] = s[t] - v;
}

__global__ __launch_bounds__(256) void k_rowptr(const int* __restrict__ cnt,
                                                const int* __restrict__ boff,
                                                int* __restrict__ row_ptr,
                                                int* __restrict__ cursor,
                                                float* __restrict__ dinv) {
    __shared__ int s[256];
    int t = threadIdx.x;
    int i = blockIdx.x * 256 + t;
    int v = (i < N_NODES) ? cnt[i] : 0;
    s[t] = v;
    __syncthreads();
    for (int o = 1; o < 256; o <<= 1) {
        int u = (t >= o) ? s[t - o] : 0;
        __syncthreads();
        s[t] += u;
        __syncthreads();
    }
    int excl = boff[blockIdx.x] + s[t] - v;
    if (i < N_NODES) {
        row_ptr[i] = excl;
        cursor[i]  = excl;
        dinv[i]    = rsqrtf((float)(v + 1));
    } else if (i == N_NODES) {
        row_ptr[N_NODES] = excl;
    }
}

__global__ void k_fill(const int* __restrict__ src, const int* __restrict__ dst,
                       const float* __restrict__ dinv, int* __restrict__ cursor,
                       int* __restrict__ col, float* __restrict__ wnorm) {
    int e = blockIdx.x * blockDim.x + threadIdx.x;
    if (e < N_EDGES) {
        int d = dst[e], s = src[e];
        int pos = atomicAdd(&cursor[d], 1);
        col[pos]   = s;
        wnorm[pos] = dinv[s] * dinv[d];
    }
}

__global__ void k_granges(const int* __restrict__ batch,
                          unsigned* __restrict__ gstart, unsigned* __restrict__ gend) {
    int i = blockIdx.x * blockDim.x + threadIdx.x;
    if (i < N_NODES) {
        int g = batch[i];
        atomicMin(&gstart[g], (unsigned)i);
        atomicMax(&gend[g],   (unsigned)(i + 1));
    }
}

// ---------------------------------------------------------------- aggregation
// one wave per node, float2/lane; 8 gathers always in flight (OOB slots clamp
// to the row's last edge -> same cacheline -> cheap, weight zeroed).
__global__ __launch_bounds__(256) void k_agg(const float* __restrict__ hin,
                                             float* __restrict__ agg,
                                             const float* __restrict__ dinv,
                                             const int* __restrict__ row_ptr,
                                             const int* __restrict__ col,
                                             const float* __restrict__ wnorm) {
    int node = blockIdx.x * 4 + (threadIdx.x >> 6);
    if (node >= N_NODES) return;
    int lane = threadIdx.x & 63;
    const float2* __restrict__ hin2 = (const float2*)hin + lane;
    float di = dinv[node];
    float2 v = hin2[(size_t)node * 64];
    float2 acc; acc.x = v.x * di * di; acc.y = v.y * di * di;   // self-loop
    int e0 = __builtin_amdgcn_readfirstlane(row_ptr[node]);
    int e1 = __builtin_amdgcn_readfirstlane(row_ptr[node + 1]);
    if (e0 < e1) {
        const int last = e1 - 1;
        for (int e = e0; e < e1; e += 8) {
            int j[8]; float wt[8];
#pragma unroll
            for (int i = 0; i < 8; ++i) {
                int ee = e + i;
                int cl = (ee <= last) ? ee : last;
                j[i]  = col[cl];
                wt[i] = (ee <= last) ? wnorm[cl] : 0.f;
            }
            float2 u[8];
#pragma unroll
            for (int i = 0; i < 8; ++i) u[i] = hin2[(size_t)j[i] * 64];
#pragma unroll
            for (int i = 0; i < 8; ++i) {
                acc.x += u[i].x * wt[i];
                acc.y += u[i].y * wt[i];
            }
        }
    }
    ((float2*)agg)[(size_t)node * 64 + lane] = acc;
}

// ---------------------------------------------------------------- GEMM (W-stationary)
// out = relu(A @ W + b). Each wave owns 32 cols; lane holds its W column
// (64 f32 VGPRs, k-half = lane>>5). Rows staged 8/chunk in LDS (double-buffered,
// reg-prefetch), consumed as broadcast ds_read_b128. VALU floor ~10.4us/layer.
__global__ __launch_bounds__(256, 4) void k_gemm(const float* __restrict__ A,
                                                 const float* __restrict__ W,
                                                 const float* __restrict__ bias,
                                                 float* __restrict__ out) {
    __shared__ float Al[2][8][128];

    const int tid  = threadIdx.x;
    const int wv   = tid >> 6;
    const int lane = tid & 63;
    const int kh   = lane >> 5;               // k-half: 0 -> k 0..63, 1 -> 64..127
    const int c    = wv * 32 + (lane & 31);   // my output column

    float w[64];
    {
        const float* Wp = W + (size_t)(kh * 64) * DIM + c;
#pragma unroll
        for (int k = 0; k < 64; ++k) w[k] = Wp[(size_t)k * DIM];
    }
    const float bv = bias[c];

    const int srow = tid >> 5;   // staging row 0..7
    const int slot = tid & 31;   // float4 slot

    int chunk = blockIdx.x;
    {
        float4 rv = *(const float4*)&A[((size_t)chunk * 8 + srow) * DIM + slot * 4];
        *(float4*)&Al[0][srow][slot * 4] = rv;
    }
    __syncthreads();

    for (int it = 0; it < GEMM_ITERS; ++it) {
        const int b = it & 1;
        float4 pf;
        if (it < GEMM_ITERS - 1) {
            int nchunk = chunk + GEMM_GRID;
            pf = *(const float4*)&A[((size_t)nchunk * 8 + srow) * DIM + slot * 4];
        }

        float acc[8] = {};
#pragma unroll
        for (int k4 = 0; k4 < 16; ++k4) {
            float4 r[8];
#pragma unroll
            for (int n = 0; n < 8; ++n)
                r[n] = *(const float4*)&Al[b][n][kh * 64 + k4 * 4];
#pragma unroll
            for (int n = 0; n < 8; ++n) {
                acc[n] += r[n].x * w[k4 * 4 + 0];
                acc[n] += r[n].y * w[k4 * 4 + 1];
                acc[n] += r[n].z * w[k4 * 4 + 2];
                acc[n] += r[n].w * w[k4 * 4 + 3];
            }
        }
        __syncthreads();                       // all waves done reading buf b
        if (it < GEMM_ITERS - 1)
            *(float4*)&Al[b ^ 1][srow][slot * 4] = pf;

        // finalize this chunk (no LDS use -> overlaps the ds_write)
#pragma unroll
        for (int n = 0; n < 8; ++n) {
            float full = acc[n] + __shfl_xor(acc[n], 32, 64);
            if (kh == 0) {
                int node = chunk * 8 + n;
                out[(size_t)node * DIM + c] = fmaxf(full + bv, 0.f);
            }
        }
        if (it < GEMM_ITERS - 1) __syncthreads();  // write visible before next read
        chunk += GEMM_GRID;
    }
}

// ---------------------------------------------------------------- pooling
// batch sorted -> contiguous ranges; 512 threads, 16-way row split, float4.
__global__ __launch_bounds__(512) void k_pool(const float* __restrict__ h,
                                              const unsigned* __restrict__ gstart,
                                              const unsigned* __restrict__ gend,
                                              float* __restrict__ out, int layer) {
    __shared__ float4 red[16][32];
    int g    = blockIdx.x;
    int slot = threadIdx.x & 31;   // float4 slot 0..31
    int way  = threadIdx.x >> 5;   // 0..15
    unsigned s = gstart[g], e = gend[g];
    float4 sum = make_float4(0.f, 0.f, 0.f, 0.f);
    if (s != 0xFFFFFFFFu) {
        for (unsigned i = s + way; i < e; i += 16) {
            float4 v = *(const float4*)&h[(size_t)i * DIM + slot * 4];
            sum.x += v.x; sum.y += v.y; sum.z += v.z; sum.w += v.w;
        }
    }
    red[way][slot] = sum;
    __syncthreads();
    if (threadIdx.x < 32) {
        float4 t = red[0][slot];
#pragma unroll
        for (int wy = 1; wy < 16; ++wy) {
            float4 v = red[wy][slot];
            t.x += v.x; t.y += v.y; t.z += v.z; t.w += v.w;
        }
        *(float4*)&out[(size_t)g * (N_LAYERS * DIM) + layer * DIM + slot * 4] = t;
    }
}

// ---------------------------------------------------------------- launch

extern "C" void kernel_launch(void* const* d_in, const int* in_sizes, int n_in,
                              void* d_out, int out_size, void* d_ws, size_t ws_size,
                              hipStream_t stream) {
    const float* x    = (const float*)d_in[0];
    const int*   ei   = (const int*)d_in[1];
    const int*   bat  = (const int*)d_in[2];
    const float* Ws   = (const float*)d_in[3];
    const float* bs   = (const float*)d_in[4];
    float*       outp = (float*)d_out;

    const int* srcp = ei;
    const int* dstp = ei + N_EDGES;

    char* base = (char*)d_ws;
    size_t off = 0;
    float*    hP      = (float*)(base + off); off += (size_t)N_NODES * DIM * 4;
    float*    hQ      = (float*)(base + off); off += (size_t)N_NODES * DIM * 4;
    float*    dinv    = (float*)(base + off); off += (size_t)N_NODES * 4;
    int*      cnt     = (int*)(base + off);   off += (size_t)N_NODES * 4;
    int*      row_ptr = (int*)(base + off);   off += 200016;
    int*      cursor  = (int*)(base + off);   off += (size_t)N_NODES * 4;
    int*      col     = (int*)(base + off);   off += (size_t)N_EDGES * 4;
    float*    wnorm   = (float*)(base + off); off += (size_t)N_EDGES * 4;
    int*      bsum    = (int*)(base + off);   off += 1024;
    int*      boff    = (int*)(base + off);   off += 1024;
    unsigned* gstart  = (unsigned*)(base + off); off += 2048;
    unsigned* gend    = (unsigned*)(base + off); off += 2048;

    hipMemsetAsync(cnt,    0,    (size_t)N_NODES * 4, stream);
    hipMemsetAsync(gstart, 0xFF, 2048, stream);
    hipMemsetAsync(gend,   0,    2048, stream);

    const int BE = (N_EDGES + 255) / 256;

    k_count<<<BE, 256, 0, stream>>>(dstp, cnt);
    k_bsum<<<NB, 256, 0, stream>>>(cnt, bsum);
    k_scan_bsum<<<1, 256, 0, stream>>>(bsum, boff);
    k_rowptr<<<NB, 256, 0, stream>>>(cnt, boff, row_ptr, cursor, dinv);
    k_fill<<<BE, 256, 0, stream>>>(srcp, dstp, dinv, cursor, col, wnorm);
    k_granges<<<NB, 256, 0, stream>>>(bat, gstart, gend);

    const int BAGG = (N_NODES + 3) / 4;

    for (int l = 0; l < N_LAYERS; ++l) {
        const float* hin = (l == 0) ? x : hQ;
        k_agg<<<BAGG, 256, 0, stream>>>(hin, hP, dinv, row_ptr, col, wnorm);
        k_gemm<<<GEMM_GRID, 256, 0, stream>>>(hP, Ws + (size_t)l * DIM * DIM,
                                              bs + (size_t)l * DIM, hQ);
        k_pool<<<N_GRAPHS, 512, 0, stream>>>(hQ, gstart, gend, outp, l);
    }
}

// Round 4
// 575.083 us; speedup vs baseline: 11.2019x; 11.2019x over previous
//
#include <hip/hip_runtime.h>

#define N_NODES  50000
#define N_EDGES  600000
#define DIM      128
#define N_LAYERS 5
#define N_GRAPHS 512
#define NB       ((N_NODES + 255) / 256)   // 196 scan blocks

// ---------------------------------------------------------------- preprocess

__global__ void k_count(const int* __restrict__ dst, int* __restrict__ cnt) {
    int e = blockIdx.x * blockDim.x + threadIdx.x;
    if (e < N_EDGES) atomicAdd(&cnt[dst[e]], 1);
}

__global__ __launch_bounds__(256) void k_bsum(const int* __restrict__ cnt,
                                              int* __restrict__ bsum) {
    __shared__ int ws[4];
    int i = blockIdx.x * 256 + threadIdx.x;
    int v = (i < N_NODES) ? cnt[i] : 0;
#pragma unroll
    for (int o = 32; o > 0; o >>= 1) v += __shfl_down(v, o, 64);
    if ((threadIdx.x & 63) == 0) ws[threadIdx.x >> 6] = v;
    __syncthreads();
    if (threadIdx.x == 0) bsum[blockIdx.x] = ws[0] + ws[1] + ws[2] + ws[3];
}

__global__ void k_scan_bsum(const int* __restrict__ bsum, int* __restrict__ boff) {
    __shared__ int s[256];
    int t = threadIdx.x;
    int v = (t < NB) ? bsum[t] : 0;
    s[t] = v;
    __syncthreads();
    for (int o = 1; o < 256; o <<= 1) {
        int u = (t >= o) ? s[t - o] : 0;
        __syncthreads();
        s[t] += u;
        __syncthreads();
    }
    if (t < NB) boff[t] = s[t] - v;
}

__global__ __launch_bounds__(256) void k_rowptr(const int* __restrict__ cnt,
                                                const int* __restrict__ boff,
                                                int* __restrict__ row_ptr,
                                                int* __restrict__ cursor,
                                                float* __restrict__ dinv) {
    __shared__ int s[256];
    int t = threadIdx.x;
    int i = blockIdx.x * 256 + t;
    int v = (i < N_NODES) ? cnt[i] : 0;
    s[t] = v;
    __syncthreads();
    for (int o = 1; o < 256; o <<= 1) {
        int u = (t >= o) ? s[t - o] : 0;
        __syncthreads();
        s[t] += u;
        __syncthreads();
    }
    int excl = boff[blockIdx.x] + s[t] - v;
    if (i < N_NODES) {
        row_ptr[i] = excl;
        cursor[i]  = excl;
        dinv[i]    = rsqrtf((float)(v + 1));
    } else if (i == N_NODES) {
        row_ptr[N_NODES] = excl;
    }
}

__global__ void k_fill(const int* __restrict__ src, const int* __restrict__ dst,
                       const float* __restrict__ dinv, int* __restrict__ cursor,
                       int* __restrict__ col, float* __restrict__ wnorm) {
    int e = blockIdx.x * blockDim.x + threadIdx.x;
    if (e < N_EDGES) {
        int d = dst[e], s = src[e];
        int pos = atomicAdd(&cursor[d], 1);
        col[pos]   = s;
        wnorm[pos] = dinv[s] * dinv[d];
    }
}

__global__ void k_granges(const int* __restrict__ batch,
                          unsigned* __restrict__ gstart, unsigned* __restrict__ gend) {
    int i = blockIdx.x * blockDim.x + threadIdx.x;
    if (i < N_NODES) {
        int g = batch[i];
        atomicMin(&gstart[g], (unsigned)i);
        atomicMax(&gend[g],   (unsigned)(i + 1));
    }
}

// ---------------------------------------------------------------- aggregation
// half-wave per node: 2 nodes/wave, float4/lane (32 lanes * 16B = 512B row).
// 8-deep unroll -> 16 row-gathers in flight per wave. OOB slots clamp to the
// row's last edge (same cacheline, weight 0). Grid covers N exactly.
__global__ __launch_bounds__(256) void k_agg(const float* __restrict__ hin,
                                             float* __restrict__ agg,
                                             const float* __restrict__ dinv,
                                             const int* __restrict__ row_ptr,
                                             const int* __restrict__ col,
                                             const float* __restrict__ wnorm) {
    const int wid  = blockIdx.x * 4 + (threadIdx.x >> 6);
    const int half = (threadIdx.x >> 5) & 1;
    const int node = wid * 2 + half;            // 6250*4*2 = 50000 exactly
    const int slot = threadIdx.x & 31;
    const float4* __restrict__ hin4 = (const float4*)hin + slot;

    float di = dinv[node];
    float4 v = hin4[(size_t)node * 32];
    float4 acc;
    acc.x = v.x * di * di; acc.y = v.y * di * di;   // self-loop
    acc.z = v.z * di * di; acc.w = v.w * di * di;

    int e0 = row_ptr[node], e1 = row_ptr[node + 1];
    const int last = e1 - 1;
    for (int e = e0; e < e1; e += 8) {
        int jj[8]; float wt[8];
#pragma unroll
        for (int i = 0; i < 8; ++i) {
            int ee = e + i;
            int cl = (ee <= last) ? ee : last;
            jj[i] = col[cl];
            wt[i] = (ee <= last) ? wnorm[cl] : 0.f;
        }
        float4 u[8];
#pragma unroll
        for (int i = 0; i < 8; ++i) u[i] = hin4[(size_t)jj[i] * 32];
#pragma unroll
        for (int i = 0; i < 8; ++i) {
            acc.x += u[i].x * wt[i]; acc.y += u[i].y * wt[i];
            acc.z += u[i].z * wt[i]; acc.w += u[i].w * wt[i];
        }
    }
    ((float4*)agg)[(size_t)node * 32 + slot] = acc;
}

// ---------------------------------------------------------------- GEMM + bias + relu
// out = relu(A @ W + b). Full W in LDS (64KB, staged once, 1 barrier).
// 64-row tile, 256 threads, 8 rows x 4 cols per thread. A read straight from
// global: 32 lanes of a row-group share the address (broadcast, L1-resident
// 32KB working set), double-buffered in named reg arrays (static idx only).
// Per k4: 8 global b128 + 4 LDS b128 + 128 FMA-instr -> VALU-bound.
__global__ __launch_bounds__(256, 2) void k_gemm(const float* __restrict__ A,
                                                 const float* __restrict__ W,
                                                 const float* __restrict__ bias,
                                                 float* __restrict__ out) {
    __shared__ float4 Wl[DIM * 32];     // [k][c4], 65536 B

    const int tid = threadIdx.x;
    const int tc  = tid & 31;           // cols tc*4 .. tc*4+3
    const int tr  = tid >> 5;           // rows tr*8 .. tr*8+7
    const int rb  = blockIdx.x * 64;

    const float4* Wg = (const float4*)W;
#pragma unroll
    for (int i = 0; i < 16; ++i) Wl[tid + i * 256] = Wg[tid + i * 256];
    __syncthreads();

    const float4* ap[8];
#pragma unroll
    for (int r = 0; r < 8; ++r) {
        int crow = rb + tr * 8 + r;
        if (crow > N_NODES - 1) crow = N_NODES - 1;   // clamp loads; store guarded
        ap[r] = (const float4*)A + (size_t)crow * 32;
    }

    float acc[8][4] = {};
    float4 a0[8], a1[8];
#pragma unroll
    for (int r = 0; r < 8; ++r) a0[r] = ap[r][0];

#define GEMM_STEP(AF, PF, K4)                                             \
    {                                                                     \
        _Pragma("unroll")                                                 \
        for (int r = 0; r < 8; ++r) PF[r] = ap[r][(K4) + 1];              \
        float4 w0 = Wl[((K4) * 4 + 0) * 32 + tc];                         \
        float4 w1 = Wl[((K4) * 4 + 1) * 32 + tc];                         \
        float4 w2 = Wl[((K4) * 4 + 2) * 32 + tc];                         \
        float4 w3 = Wl[((K4) * 4 + 3) * 32 + tc];                         \
        _Pragma("unroll")                                                 \
        for (int r = 0; r < 8; ++r) {                                     \
            acc[r][0] += AF[r].x * w0.x; acc[r][1] += AF[r].x * w0.y;     \
            acc[r][2] += AF[r].x * w0.z; acc[r][3] += AF[r].x * w0.w;     \
            acc[r][0] += AF[r].y * w1.x; acc[r][1] += AF[r].y * w1.y;     \
            acc[r][2] += AF[r].y * w1.z; acc[r][3] += AF[r].y * w1.w;     \
            acc[r][0] += AF[r].z * w2.x; acc[r][1] += AF[r].z * w2.y;     \
            acc[r][2] += AF[r].z * w2.z; acc[r][3] += AF[r].z * w2.w;     \
            acc[r][0] += AF[r].w * w3.x; acc[r][1] += AF[r].w * w3.y;     \
            acc[r][2] += AF[r].w * w3.z; acc[r][3] += AF[r].w * w3.w;     \
        }                                                                 \
    }

    // final prefetch reads 16B past row 49999 -> lands in hQ region of d_ws: safe.
    for (int k8 = 0; k8 < 16; ++k8) {
        GEMM_STEP(a0, a1, 2 * k8)
        GEMM_STEP(a1, a0, 2 * k8 + 1)
    }
#undef GEMM_STEP

    float4 bv = ((const float4*)bias)[tc];
#pragma unroll
    for (int r = 0; r < 8; ++r) {
        int grow = rb + tr * 8 + r;
        if (grow < N_NODES) {
            float4 o;
            o.x = fmaxf(acc[r][0] + bv.x, 0.f);
            o.y = fmaxf(acc[r][1] + bv.y, 0.f);
            o.z = fmaxf(acc[r][2] + bv.z, 0.f);
            o.w = fmaxf(acc[r][3] + bv.w, 0.f);
            ((float4*)out)[(size_t)grow * 32 + tc] = o;
        }
    }
}

// ---------------------------------------------------------------- pooling
__global__ __launch_bounds__(512) void k_pool(const float* __restrict__ h,
                                              const unsigned* __restrict__ gstart,
                                              const unsigned* __restrict__ gend,
                                              float* __restrict__ out, int layer) {
    __shared__ float4 red[16][32];
    int g    = blockIdx.x;
    int slot = threadIdx.x & 31;
    int way  = threadIdx.x >> 5;
    unsigned s = gstart[g], e = gend[g];
    float4 sum = make_float4(0.f, 0.f, 0.f, 0.f);
    if (s != 0xFFFFFFFFu) {
        for (unsigned i = s + way; i < e; i += 16) {
            float4 v = *(const float4*)&h[(size_t)i * DIM + slot * 4];
            sum.x += v.x; sum.y += v.y; sum.z += v.z; sum.w += v.w;
        }
    }
    red[way][slot] = sum;
    __syncthreads();
    if (threadIdx.x < 32) {
        float4 t = red[0][slot];
#pragma unroll
        for (int wy = 1; wy < 16; ++wy) {
            float4 v = red[wy][slot];
            t.x += v.x; t.y += v.y; t.z += v.z; t.w += v.w;
        }
        *(float4*)&out[(size_t)g * (N_LAYERS * DIM) + layer * DIM + slot * 4] = t;
    }
}

// ---------------------------------------------------------------- launch

extern "C" void kernel_launch(void* const* d_in, const int* in_sizes, int n_in,
                              void* d_out, int out_size, void* d_ws, size_t ws_size,
                              hipStream_t stream) {
    const float* x    = (const float*)d_in[0];
    const int*   ei   = (const int*)d_in[1];
    const int*   bat  = (const int*)d_in[2];
    const float* Ws   = (const float*)d_in[3];
    const float* bs   = (const float*)d_in[4];
    float*       outp = (float*)d_out;

    const int* srcp = ei;
    const int* dstp = ei + N_EDGES;

    char* base = (char*)d_ws;
    size_t off = 0;
    float*    hP      = (float*)(base + off); off += (size_t)N_NODES * DIM * 4;
    float*    hQ      = (float*)(base + off); off += (size_t)N_NODES * DIM * 4;
    float*    dinv    = (float*)(base + off); off += (size_t)N_NODES * 4;
    int*      cnt     = (int*)(base + off);   off += (size_t)N_NODES * 4;
    int*      row_ptr = (int*)(base + off);   off += 200016;
    int*      cursor  = (int*)(base + off);   off += (size_t)N_NODES * 4;
    int*      col     = (int*)(base + off);   off += (size_t)N_EDGES * 4;
    float*    wnorm   = (float*)(base + off); off += (size_t)N_EDGES * 4;
    int*      bsum    = (int*)(base + off);   off += 1024;
    int*      boff    = (int*)(base + off);   off += 1024;
    unsigned* gstart  = (unsigned*)(base + off); off += 2048;
    unsigned* gend    = (unsigned*)(base + off); off += 2048;

    hipMemsetAsync(cnt,    0,    (size_t)N_NODES * 4, stream);
    hipMemsetAsync(gstart, 0xFF, 2048, stream);
    hipMemsetAsync(gend,   0,    2048, stream);

    const int BE = (N_EDGES + 255) / 256;

    k_count<<<BE, 256, 0, stream>>>(dstp, cnt);
    k_bsum<<<NB, 256, 0, stream>>>(cnt, bsum);
    k_scan_bsum<<<1, 256, 0, stream>>>(bsum, boff);
    k_rowptr<<<NB, 256, 0, stream>>>(cnt, boff, row_ptr, cursor, dinv);
    k_fill<<<BE, 256, 0, stream>>>(srcp, dstp, dinv, cursor, col, wnorm);
    k_granges<<<NB, 256, 0, stream>>>(bat, gstart, gend);

    const int BAGG  = 6250;                   // 6250*4 waves*2 nodes = 50000
    const int BGEMM = (N_NODES + 63) / 64;    // 782

    for (int l = 0; l < N_LAYERS; ++l) {
        const float* hin = (l == 0) ? x : hQ;
        k_agg<<<BAGG, 256, 0, stream>>>(hin, hP, dinv, row_ptr, col, wnorm);
        k_gemm<<<BGEMM, 256, 0, stream>>>(hP, Ws + (size_t)l * DIM * DIM,
                                          bs + (size_t)l * DIM, hQ);
        k_pool<<<N_GRAPHS, 512, 0, stream>>>(hQ, gstart, gend, outp, l);
    }
}